// Round 20
// baseline (156.099 us; speedup 1.0000x reference)
//
#include <hip/hip_runtime.h>
#include <stdint.h>

typedef unsigned long long u64;
typedef unsigned int u32;

#define NA 250000
#define NC 80
#define KP 2000
#define MD 300
#define CAP 4096
#define SCORE_TH 0.05f

#define WG __HIP_MEMORY_SCOPE_WORKGROUP

// ---- ws layout (bytes) ----
// sbits  u32[250000]      @ 0
// amax   u32[250000]      @ 1000000
// state  u32[16]          @ 2000000   [0]=prefix11 [1]=k [2]=pivot [3]=n_cand [5]=done0 [6]=done1
// hist0  u32[2048]        @ 2000064
// hist1  u32[2048]        @ 2008256
// cand   u64[4096]        @ 2016448
// canda  u32[2048]        @ 2049216
// cands  u32[2048]        @ 2057408
// boxesg float4[2048]     @ 2065600
// supT   u64[32][2048]    @ 2098368   (transposed: supT[w][i] = word w of row i)
// pad    u64[2][2048]     @ 2622656   (read-only overrun pad for words 32/33 stage)

__device__ __forceinline__ u32 ald(const u32* p) {
    return __hip_atomic_load(p, __ATOMIC_RELAXED, __HIP_MEMORY_SCOPE_AGENT);
}
__device__ __forceinline__ void ast(u32* p, u32 v) {
    __hip_atomic_store(p, v, __ATOMIC_RELAXED, __HIP_MEMORY_SCOPE_AGENT);
}

__device__ __forceinline__ u64 readlane_u64(u64 v, int b) {
    u32 lo = (u32)__builtin_amdgcn_readlane((int)(u32)v, b);
    u32 hi = (u32)__builtin_amdgcn_readlane((int)(u32)(v >> 32), b);
    return ((u64)hi << 32) | lo;
}

__device__ __forceinline__ float4 decode_box(const float* __restrict__ anchors,
                                             const float* __restrict__ reg, u32 a) {
    float4 an = ((const float4*)anchors)[a];
    float4 rg = ((const float4*)reg)[a];
    float w = an.z - an.x, h = an.w - an.y;
    float cx = an.x + 0.5f * w, cy = an.y + 0.5f * h;
    float pcx = cx + (rg.x * 0.1f) * w;
    float pcy = cy + (rg.y * 0.1f) * h;
    float pw = expf(rg.z * 0.2f) * w;
    float ph = expf(rg.w * 0.2f) * h;
    float x1 = fmaxf(pcx - 0.5f * pw, 0.0f);
    float y1 = fmaxf(pcy - 0.5f * ph, 0.0f);
    float x2 = fminf(pcx + 0.5f * pw, 512.0f);
    float y2 = fminf(pcy + 0.5f * ph, 512.0f);
    return make_float4(x1, y1, x2, y2);
}

// scores + argmax; 245 blocks x 4 grid-stride sweeps (narrow grid = less ramp).
__global__ __launch_bounds__(256) void k_score(const float* __restrict__ cls,
                                               u32* __restrict__ sbits,
                                               u32* __restrict__ amax,
                                               u32* __restrict__ state,
                                               u32* __restrict__ hist0,
                                               u32* __restrict__ hist1) {
    __shared__ float vs[256 * 21];
    __shared__ unsigned short ci[256 * 21];
    int t = threadIdx.x;
    if (blockIdx.x == 0) {
        if (t < 16) state[t] = (t == 1) ? (u32)KP : 0u;
        for (int i = t; i < 2048; i += 256) { hist0[i] = 0; hist1[i] = 0; }
    }
    const float4* cv = (const float4*)cls;
    for (int B0 = blockIdx.x * 256; B0 < NA; B0 += 245 * 256) {
        const int base4 = B0 * 20;
#pragma unroll 5
        for (int r = 0; r < 20; ++r) {
            int gi = base4 + r * 256 + t;
            if (gi < NA * 20) {
                float4 v = cv[gi];
                int a = gi / 20;
                int j = gi - a * 20;
                float best = v.x; int c = 0;
                if (v.y > best) { best = v.y; c = 1; }
                if (v.z > best) { best = v.z; c = 2; }
                if (v.w > best) { best = v.w; c = 3; }
                int la = a - B0;
                vs[la * 21 + j] = best;
                ci[la * 21 + j] = (unsigned short)(j * 4 + c);
            }
        }
        __syncthreads();
        int a = B0 + t;
        if (a < NA) {
            float best = vs[t * 21]; int bi = ci[t * 21];
#pragma unroll
            for (int j = 1; j < 20; ++j) {
                float v = vs[t * 21 + j];
                if (v > best) { best = v; bi = ci[t * 21 + j]; }
            }
            sbits[a] = (best > SCORE_TH) ? __float_as_uint(best) : 0u;
            amax[a] = (u32)bi;
        }
        __syncthreads();                       // LDS reuse across sweeps
    }
}

__device__ __forceinline__ void pick_body(u32* state, const u32* hist, int p) {
    int lane = threadIdx.x;                   // caller ensures lane<64
    int hi = 2048 - lane * 32;
    int lo = hi - 32;
    u32 h32[32];
#pragma unroll
    for (int x = 0; x < 32; ++x) h32[x] = ald(&hist[lo + x]);
    u32 s = 0;
#pragma unroll
    for (int x = 0; x < 32; ++x) s += h32[x];
    u32 sc = s;
#pragma unroll
    for (int d = 1; d < 64; d <<= 1) {
        u32 tv = __shfl_up(sc, d);
        if (lane >= d) sc += tv;
    }
    u32 pre = sc - s;
    u32 kk = ald(&state[1]);
    if (pre < kk && kk <= sc) {
        u32 c = pre; int B = lo;
        for (int x = 31; x >= 0; --x) {
            u32 h = h32[x];
            if (c + h >= kk) { B = lo + x; ast(&state[1], kk - c); break; }
            c += h;
        }
        if (p == 0) ast(&state[0], (u32)B);
        else {
            u32 prefix = ald(&state[0]);
            ast(&state[2], ((prefix << 11) | (u32)B) << 10);
        }
    }
}

// hist pass 0; 64 blocks x 4096 anchors; acq_rel RMW orders merges (no threadfence).
__global__ __launch_bounds__(256) void k_hist0(const u32* __restrict__ sbits,
                                               u32* hist0, u32* state) {
    __shared__ u32 lh[2048];
    __shared__ int is_last;
    int t = threadIdx.x;
    for (int i = t; i < 2048; i += 256) lh[i] = 0;
    __syncthreads();
    int idx = blockIdx.x * 4096;
#pragma unroll
    for (int r = 0; r < 16; ++r) {
        int a = idx + r * 256 + t;
        if (a < NA) atomicAdd(&lh[sbits[a] >> 21], 1u);
    }
    __syncthreads();
    for (int i = t; i < 2048; i += 256) { u32 h = lh[i]; if (h) atomicAdd(&hist0[i], h); }
    if (t == 0)
        is_last = (__hip_atomic_fetch_add(&state[5], 1u, __ATOMIC_ACQ_REL,
                                          __HIP_MEMORY_SCOPE_AGENT) == gridDim.x - 1);
    __syncthreads();
    if (is_last && t < 64) pick_body(state, hist0, 0);
}

__global__ __launch_bounds__(256) void k_hist1(const u32* __restrict__ sbits,
                                               u32* hist1, u32* state) {
    __shared__ u32 lh[2048];
    __shared__ int is_last;
    int t = threadIdx.x;
    u32 prefix = state[0];
    for (int i = t; i < 2048; i += 256) lh[i] = 0;
    __syncthreads();
    int idx = blockIdx.x * 4096;
#pragma unroll
    for (int r = 0; r < 16; ++r) {
        int a = idx + r * 256 + t;
        if (a < NA) {
            u32 bb = sbits[a];
            if ((bb >> 21) == prefix) atomicAdd(&lh[(bb >> 10) & 0x7FFu], 1u);
        }
    }
    __syncthreads();
    for (int i = t; i < 2048; i += 256) { u32 h = lh[i]; if (h) atomicAdd(&hist1[i], h); }
    if (t == 0)
        is_last = (__hip_atomic_fetch_add(&state[6], 1u, __ATOMIC_ACQ_REL,
                                          __HIP_MEMORY_SCOPE_AGENT) == gridDim.x - 1);
    __syncthreads();
    if (is_last && t < 64) pick_body(state, hist1, 1);
}

// collect: 64 blocks x 4096 anchors, LDS-aggregated, one global atomic per block.
__global__ __launch_bounds__(256) void k_collect(const u32* __restrict__ sbits,
                                                 u32* state, u64* __restrict__ cand) {
    __shared__ u64 lbuf[2048];
    __shared__ u32 lcount;
    __shared__ u32 gbase;
    int t = threadIdx.x;
    if (t == 0) lcount = 0;
    __syncthreads();
    u32 pivot = state[2];
    int idx = blockIdx.x * 4096;
#pragma unroll
    for (int r = 0; r < 16; ++r) {
        int a = idx + r * 256 + t;
        if (a < NA) {
            u32 b = sbits[a];
            if (b != 0u && b >= pivot) {
                u32 s = atomicAdd(&lcount, 1u);
                if (s < 2048u) lbuf[s] = ((u64)b << 32) | (u32)(~(u32)a);
            }
        }
    }
    __syncthreads();
    u32 n = lcount; if (n > 2048u) n = 2048u;
    if (t == 0 && n > 0) gbase = atomicAdd(&state[3], n);
    __syncthreads();
    if (n > 0) {
        u32 base = gbase;
        for (u32 i = t; i < n; i += 256) {
            u32 slot = base + i;
            if (slot < CAP) cand[slot] = lbuf[i];
        }
    }
}

// rank-sort + box decode: 64 blocks x 64 candidates; thread (li,seg) counts a
// 1024-key segment (4 segs cover all 4096 slots).
__global__ __launch_bounds__(256) void k_rank(const u32* __restrict__ state,
                                              const u64* __restrict__ cand,
                                              u32* __restrict__ canda, u32* __restrict__ cands,
                                              float4* __restrict__ boxesg,
                                              const float* __restrict__ anchors,
                                              const float* __restrict__ reg) {
    __shared__ u64 tile[CAP];
    __shared__ u32 pr2[64][5];
    int t = threadIdx.x;
    int n = (int)state[3]; if (n > CAP) n = CAP;
    for (int i = t; i < CAP; i += 256) tile[i] = (i < n) ? cand[i] : 0ull;
    if (blockIdx.x == 0) {
        for (int i = n + t; i < 2048; i += 256) {
            canda[i] = 0u; cands[i] = 0u;
            boxesg[i] = make_float4(0.f, 0.f, 0.f, 0.f);
        }
    }
    __syncthreads();
    int li = t & 63, seg = t >> 6;
    u64 my = tile[blockIdx.x * 64 + li];
    u32 r = 0;
    int j0 = seg * 1024;
#pragma unroll 8
    for (int j = j0; j < j0 + 1024; ++j) r += (tile[j] > my) ? 1u : 0u;
    pr2[li][seg] = r;
    __syncthreads();
    if (t < 64) {
        int ci = blockIdx.x * 64 + t;
        if (ci < n) {
            u32 rk = pr2[t][0] + pr2[t][1] + pr2[t][2] + pr2[t][3];
            u64 kx = tile[ci];
            u32 a = ~((u32)kx);
            if (rk < 2048u) {
                canda[rk] = a;
                cands[rk] = (u32)(kx >> 32);
                boxesg[rk] = decode_box(anchors, reg, a);
            }
        }
    }
}

// IoU bitmask, transposed supT: 64 blocks x 16 wave-tiles (jb is wave-private,
// no barriers needed between iterations).
__global__ __launch_bounds__(256) void k_iou(const float4* __restrict__ boxesg,
                                             u64* __restrict__ supT) {
    __shared__ float4 jb[4][64];
    int t = threadIdx.x;
    int wv = t >> 6, lane = t & 63;
    for (int it = 0; it < 4; ++it) {
        int W = blockIdx.x * 16 + it * 4 + wv;   // 0..1023
        int bi = W >> 5, bj = W & 31;
        int j0 = bj * 64;
        jb[wv][lane] = boxesg[j0 + lane];
        int i = bi * 64 + lane;
        if (i >= KP) continue;
        u64 word = 0ull;
        if (bj >= bi) {
            int jn = KP - j0; if (jn > 64) jn = 64;
            float4 bx = boxesg[i];
            float ai = (bx.z - bx.x) * (bx.w - bx.y);
            for (int jj = 0; jj < jn; ++jj) {
                if (j0 + jj <= i) continue;
                float4 b2 = jb[wv][jj];
                float aj = (b2.z - b2.x) * (b2.w - b2.y);
                float xx1 = fmaxf(bx.x, b2.x), yy1 = fmaxf(bx.y, b2.y);
                float xx2 = fminf(bx.z, b2.z), yy2 = fminf(bx.w, b2.w);
                float iw = xx2 - xx1; if (iw < 0.f) iw = 0.f;
                float ih = yy2 - yy1; if (ih < 0.f) ih = 0.f;
                float inter = iw * ih;
                float iou = inter / (ai + aj - inter + 1e-9f);
                if (iou > 0.1f) word |= (1ull << jj);
            }
        }
        supT[(size_t)bj * 2048 + i] = word;
    }
}

// serial greedy NMS, producer/consumer (R19, unchanged): 4 waves, 1 block.
__global__ __launch_bounds__(256, 1) void k_scan(const u64* __restrict__ supT,
                                                 const u32* __restrict__ cands,
                                                 const u32* __restrict__ canda,
                                                 const u32* __restrict__ amax,
                                                 const float4* __restrict__ boxesg,
                                                 float* __restrict__ out) {
    __shared__ u64 stage[16][4][128];    // 64 KB  [C][word][row]
    __shared__ float scnd[2048];
    __shared__ int klist[2048];
    __shared__ int kcAt[17];
    __shared__ u32 removedLo[32], removedHi[32];
    __shared__ u32 stage_done[16];
    __shared__ u32 kdone;
    __shared__ u32 fold_done;

    int t = threadIdx.x;
    int wv = t >> 6, lane = t & 63;
    if (t < 16) stage_done[t] = 0;
    if (t < 32) { removedLo[t] = 0; removedHi[t] = 0; }
    if (t == 0) { kdone = 0; fold_done = 0; kcAt[0] = 0; }
    __syncthreads();

    if (wv >= 2) {
        for (int C = wv - 2; C < 16; C += 2) {
            u64 v[8];
#pragma unroll
            for (int w = 0; w < 4; ++w) {
                int wa = 2 * C + w;
                v[2 * w]     = supT[(size_t)wa * 2048 + 128 * C + lane];
                v[2 * w + 1] = supT[(size_t)wa * 2048 + 128 * C + 64 + lane];
            }
            float c0 = __uint_as_float(cands[128 * C + lane]);
            float c1 = __uint_as_float(cands[128 * C + 64 + lane]);
#pragma unroll
            for (int w = 0; w < 4; ++w) {
                stage[C][w][lane] = v[2 * w];
                stage[C][w][64 + lane] = v[2 * w + 1];
            }
            scnd[128 * C + lane] = c0;
            scnd[128 * C + 64 + lane] = c1;
            __hip_atomic_store(&stage_done[C], 1u, __ATOMIC_RELEASE, WG);
        }
        return;
    }

    if (wv == 1) {
        for (int C = 0; C < 15; ++C) {
            while (__hip_atomic_load(&kdone, __ATOMIC_ACQUIRE, WG) <= (u32)C) {}
            int lo = kcAt[C], hi = kcAt[C + 1];
            int n = hi - lo;
            u64 acc = 0ull;
#pragma unroll
            for (int q = 0; q < 32; ++q) {
                int row = (q < n) ? klist[lo + q] : -1;
                u64 v = (row >= 0 && lane < 32)
                      ? supT[(size_t)lane * 2048 + row] : 0ull;
                acc |= v;
            }
            for (int q = 32; q < n; ++q) {
                int row = klist[lo + q];
                if (lane < 32) acc |= supT[(size_t)lane * 2048 + row];
            }
            if (lane < 32 && acc) {
                __hip_atomic_fetch_or(&removedLo[lane], (u32)acc, __ATOMIC_RELAXED, WG);
                __hip_atomic_fetch_or(&removedHi[lane], (u32)(acc >> 32), __ATOMIC_RELAXED, WG);
            }
            __hip_atomic_store(&fold_done, (u32)(C + 1), __ATOMIC_RELEASE, WG);
        }
        return;
    }

    // wave 0: greedy
    u64 carry0 = 0ull, carry1 = 0ull;
    int kc = 0;
    for (int C = 0; C < 16; ++C) {
        while (__hip_atomic_load(&stage_done[C], __ATOMIC_ACQUIRE, WG) == 0u) {}
        u64 m00 = stage[C][0][lane];
        u64 m01 = stage[C][1][lane];
        u64 m02 = stage[C][2][lane];
        u64 m03 = stage[C][3][lane];
        u64 m11 = stage[C][1][64 + lane];
        u64 m12 = stage[C][2][64 + lane];
        u64 m13 = stage[C][3][64 + lane];
        float cv0 = scnd[128 * C + lane];
        float cv1 = scnd[128 * C + 64 + lane];

        if (C >= 2) {
            while (__hip_atomic_load(&fold_done, __ATOMIC_ACQUIRE, WG) < (u32)(C - 1)) {}
        }
        u64 r0w = ((u64)removedHi[2 * C] << 32) | removedLo[2 * C];
        u64 r1w = ((u64)removedHi[2 * C + 1] << 32) | removedLo[2 * C + 1];
        u64 curw0 = carry0 | r0w;
        u64 curw1 = carry1 | r1w;
        u64 vm0 = __ballot(cv0 > SCORE_TH);
        u64 vm1 = __ballot(cv1 > SCORE_TH);
        if (C == 15) vm1 &= (1ull << (KP - 15 * 128 - 64)) - 1ull;

        u64 km0 = 0ull, km1 = 0ull, nc2 = 0ull, nc3 = 0ull;
        u64 rem0 = vm0 & ~curw0;
        while (rem0) {
            int bb = (int)__builtin_ctzll(rem0);
            km0 |= (1ull << bb);
            curw0 |= readlane_u64(m00, bb);
            curw1 |= readlane_u64(m01, bb);
            nc2   |= readlane_u64(m02, bb);
            nc3   |= readlane_u64(m03, bb);
            rem0 &= ~curw0;
            rem0 &= ~(1ull << bb);
        }
        u64 rem1 = vm1 & ~curw1;
        while (rem1) {
            int bb = (int)__builtin_ctzll(rem1);
            km1 |= (1ull << bb);
            curw1 |= readlane_u64(m11, bb);
            nc2   |= readlane_u64(m12, bb);
            nc3   |= readlane_u64(m13, bb);
            rem1 &= ~curw1;
            rem1 &= ~(1ull << bb);
        }

        int base = C * 128;
        int n0 = (int)__popcll(km0);
        if ((km0 >> lane) & 1ull)
            klist[kc + (int)__popcll(km0 & ((1ull << lane) - 1ull))] = base + lane;
        if ((km1 >> lane) & 1ull)
            klist[kc + n0 + (int)__popcll(km1 & ((1ull << lane) - 1ull))] = base + 64 + lane;
        kc += n0 + (int)__popcll(km1);
        if (lane == 0) kcAt[C + 1] = kc;
        carry0 = nc2; carry1 = nc3;
        __hip_atomic_store(&kdone, (u32)(C + 1), __ATOMIC_RELEASE, WG);

        if (kc >= MD) {
            if (lane == 0) {
                for (int C2 = C + 1; C2 < 16; ++C2) kcAt[C2 + 1] = kc;
            }
            __hip_atomic_store(&kdone, 16u, __ATOMIC_RELEASE, WG);
            break;
        }
    }

    // fused output: 300 slots
    int myci[5];
    u32 mya[5];
#pragma unroll
    for (int r = 0; r < 5; ++r) {
        int s = lane + r * 64;
        myci[r] = (s < MD && s < kc) ? klist[s] : -1;
    }
#pragma unroll
    for (int r = 0; r < 5; ++r) mya[r] = (myci[r] >= 0) ? canda[myci[r]] : 0u;
#pragma unroll
    for (int r = 0; r < 5; ++r) {
        int s = lane + r * 64;
        if (s >= MD) continue;
        if (myci[r] >= 0) {
            int ci = myci[r];
            u32 a = mya[r];
            u32 aa = (a >= NA) ? 0u : a;
            float4 bx = boxesg[ci];
            out[s] = __uint_as_float(cands[ci]);
            out[MD + s] = (float)amax[aa];
            out[2 * MD + 4 * s + 0] = bx.x;
            out[2 * MD + 4 * s + 1] = bx.y;
            out[2 * MD + 4 * s + 2] = bx.z;
            out[2 * MD + 4 * s + 3] = bx.w;
            out[6 * MD + s] = (float)a;
            out[7 * MD + s] = 1.0f;
        } else {
            out[s] = 0.f;
            out[MD + s] = 0.f;
            out[2 * MD + 4 * s + 0] = 0.f;
            out[2 * MD + 4 * s + 1] = 0.f;
            out[2 * MD + 4 * s + 2] = 0.f;
            out[2 * MD + 4 * s + 3] = 0.f;
            out[6 * MD + s] = -1.0f;
            out[7 * MD + s] = 0.f;
        }
    }
}

extern "C" void kernel_launch(void* const* d_in, const int* in_sizes, int n_in,
                              void* d_out, int out_size, void* d_ws, size_t ws_size,
                              hipStream_t stream) {
    const float* anchors = (const float*)d_in[1];
    const float* reg     = (const float*)d_in[2];
    const float* cls     = (const float*)d_in[3];
    float* out = (float*)d_out;
    char* ws = (char*)d_ws;

    u32* sbits    = (u32*)(ws + 0);
    u32* amax     = (u32*)(ws + 1000000);
    u32* state    = (u32*)(ws + 2000000);
    u32* hist0    = (u32*)(ws + 2000064);
    u32* hist1    = (u32*)(ws + 2008256);
    u64* cand     = (u64*)(ws + 2016448);
    u32* canda    = (u32*)(ws + 2049216);
    u32* cands    = (u32*)(ws + 2057408);
    float4* boxesg= (float4*)(ws + 2065600);
    u64* supT     = (u64*)(ws + 2098368);

    hipLaunchKernelGGL(k_score, dim3(245), dim3(256), 0, stream,
                       cls, sbits, amax, state, hist0, hist1);
    hipLaunchKernelGGL(k_hist0, dim3(64), dim3(256), 0, stream,
                       sbits, hist0, state);
    hipLaunchKernelGGL(k_hist1, dim3(64), dim3(256), 0, stream,
                       sbits, hist1, state);
    hipLaunchKernelGGL(k_collect, dim3(64), dim3(256), 0, stream,
                       sbits, state, cand);
    hipLaunchKernelGGL(k_rank, dim3(64), dim3(256), 0, stream,
                       state, cand, canda, cands, boxesg, anchors, reg);
    hipLaunchKernelGGL(k_iou, dim3(64), dim3(256), 0, stream, boxesg, supT);
    hipLaunchKernelGGL(k_scan, dim3(1), dim3(256), 0, stream,
                       supT, cands, canda, amax, boxesg, out);
}

// Round 22
// 99.991 us; speedup vs baseline: 1.5611x; 1.5611x over previous
//
#include <hip/hip_runtime.h>
#include <stdint.h>

typedef unsigned long long u64;
typedef unsigned int u32;

#define NA 250000
#define NC 80
#define KP 2000
#define MD 300
#define CAP 4096
#define SCORE_TH 0.05f

#define WG __HIP_MEMORY_SCOPE_WORKGROUP

// ---- ws layout (bytes) ----
// sbits  u32[250000]      @ 0
// amax   u32[250000]      @ 1000000
// state  u32[16]          @ 2000000   [0]=prefix11 [1]=k [2]=pivot [3]=n_cand [5]=done0 [6]=done1
// hist0  u32[2048]        @ 2000064
// hist1  u32[2048]        @ 2008256
// cand   u64[4096]        @ 2016448
// canda  u32[2048]        @ 2049216
// cands  u32[2048]        @ 2057408
// boxesg float4[2048]     @ 2065600
// supT   u64[32][2048]    @ 2098368   (transposed: supT[w][i] = word w of row i)
// pad    u64[2][2048]     @ 2622656   (read-only overrun pad for words 32/33 stage)
//
// R22 = R19 (100.3us session best), with R21's one-line launch bug fixed:
// k_collect MUST run at exactly 256 blocks (its body covers NA via 4 strided
// 65536-anchor segments per block). R21 launched it at 977 blocks -> anchors
// >=65536 collected 2-4x -> cand overflow past CAP -> broken top-2000.
// LESSON: launch geometry is part of the kernel contract.

__device__ __forceinline__ u32 ald(const u32* p) {
    return __hip_atomic_load(p, __ATOMIC_RELAXED, __HIP_MEMORY_SCOPE_AGENT);
}
__device__ __forceinline__ void ast(u32* p, u32 v) {
    __hip_atomic_store(p, v, __ATOMIC_RELAXED, __HIP_MEMORY_SCOPE_AGENT);
}

__device__ __forceinline__ u64 readlane_u64(u64 v, int b) {
    u32 lo = (u32)__builtin_amdgcn_readlane((int)(u32)v, b);
    u32 hi = (u32)__builtin_amdgcn_readlane((int)(u32)(v >> 32), b);
    return ((u64)hi << 32) | lo;
}

__device__ __forceinline__ float4 decode_box(const float* __restrict__ anchors,
                                             const float* __restrict__ reg, u32 a) {
    float4 an = ((const float4*)anchors)[a];
    float4 rg = ((const float4*)reg)[a];
    float w = an.z - an.x, h = an.w - an.y;
    float cx = an.x + 0.5f * w, cy = an.y + 0.5f * h;
    float pcx = cx + (rg.x * 0.1f) * w;
    float pcy = cy + (rg.y * 0.1f) * h;
    float pw = expf(rg.z * 0.2f) * w;
    float ph = expf(rg.w * 0.2f) * h;
    float x1 = fmaxf(pcx - 0.5f * pw, 0.0f);
    float y1 = fmaxf(pcy - 0.5f * ph, 0.0f);
    float x2 = fminf(pcx + 0.5f * pw, 512.0f);
    float y2 = fminf(pcy + 0.5f * ph, 512.0f);
    return make_float4(x1, y1, x2, y2);
}

// scores + argmax (unit-stride loads, LDS staging, init fused into block 0)
__global__ __launch_bounds__(256) void k_score(const float* __restrict__ cls,
                                               u32* __restrict__ sbits,
                                               u32* __restrict__ amax,
                                               u32* __restrict__ state,
                                               u32* __restrict__ hist0,
                                               u32* __restrict__ hist1) {
    __shared__ float vs[256 * 21];
    __shared__ unsigned short ci[256 * 21];
    int t = threadIdx.x;
    if (blockIdx.x == 0) {
        if (t < 16) state[t] = (t == 1) ? (u32)KP : 0u;
        for (int i = t; i < 2048; i += 256) { hist0[i] = 0; hist1[i] = 0; }
    }
    const int B0 = blockIdx.x * 256;
    const int base4 = B0 * 20;
    const float4* cv = (const float4*)cls;
#pragma unroll 5
    for (int r = 0; r < 20; ++r) {
        int gi = base4 + r * 256 + t;
        if (gi < NA * 20) {
            float4 v = cv[gi];
            int a = gi / 20;
            int j = gi - a * 20;
            float best = v.x; int c = 0;
            if (v.y > best) { best = v.y; c = 1; }
            if (v.z > best) { best = v.z; c = 2; }
            if (v.w > best) { best = v.w; c = 3; }
            int la = a - B0;
            vs[la * 21 + j] = best;
            ci[la * 21 + j] = (unsigned short)(j * 4 + c);
        }
    }
    __syncthreads();
    int a = B0 + t;
    if (a < NA) {
        float best = vs[t * 21]; int bi = ci[t * 21];
#pragma unroll
        for (int j = 1; j < 20; ++j) {
            float v = vs[t * 21 + j];
            if (v > best) { best = v; bi = ci[t * 21 + j]; }
        }
        sbits[a] = (best > SCORE_TH) ? __float_as_uint(best) : 0u;
        amax[a] = (u32)bi;
    }
}

__device__ __forceinline__ void pick_body(u32* state, const u32* hist, int p) {
    int lane = threadIdx.x;                   // caller ensures lane<64
    int hi = 2048 - lane * 32;
    int lo = hi - 32;
    u32 h32[32];
#pragma unroll
    for (int x = 0; x < 32; ++x) h32[x] = ald(&hist[lo + x]);
    u32 s = 0;
#pragma unroll
    for (int x = 0; x < 32; ++x) s += h32[x];
    u32 sc = s;
#pragma unroll
    for (int d = 1; d < 64; d <<= 1) {
        u32 tv = __shfl_up(sc, d);
        if (lane >= d) sc += tv;
    }
    u32 pre = sc - s;
    u32 kk = ald(&state[1]);
    if (pre < kk && kk <= sc) {
        u32 c = pre; int B = lo;
        for (int x = 31; x >= 0; --x) {
            u32 h = h32[x];
            if (c + h >= kk) { B = lo + x; ast(&state[1], kk - c); break; }
            c += h;
        }
        if (p == 0) ast(&state[0], (u32)B);
        else {
            u32 prefix = ald(&state[0]);
            ast(&state[2], ((prefix << 11) | (u32)B) << 10);
        }
    }
}

// hist pass 0; no __threadfence (acq_rel RMW orders merges; R18: -18us total).
__global__ __launch_bounds__(256) void k_hist0(const u32* __restrict__ sbits,
                                               u32* hist0, u32* state) {
    __shared__ u32 lh[2048];
    __shared__ int is_last;
    int t = threadIdx.x;
    for (int i = t; i < 2048; i += 256) lh[i] = 0;
    __syncthreads();
    int idx = blockIdx.x * 1024 + t;
#pragma unroll
    for (int r = 0; r < 4; ++r) {
        int a = idx + r * 256;
        if (a < NA) atomicAdd(&lh[sbits[a] >> 21], 1u);
    }
    __syncthreads();
    for (int i = t; i < 2048; i += 256) { u32 h = lh[i]; if (h) atomicAdd(&hist0[i], h); }
    if (t == 0)
        is_last = (__hip_atomic_fetch_add(&state[5], 1u, __ATOMIC_ACQ_REL,
                                          __HIP_MEMORY_SCOPE_AGENT) == gridDim.x - 1);
    __syncthreads();
    if (is_last && t < 64) pick_body(state, hist0, 0);
}

__global__ __launch_bounds__(256) void k_hist1(const u32* __restrict__ sbits,
                                               u32* hist1, u32* state) {
    __shared__ u32 lh[2048];
    __shared__ int is_last;
    int t = threadIdx.x;
    u32 prefix = state[0];
    for (int i = t; i < 2048; i += 256) lh[i] = 0;
    __syncthreads();
    int idx = blockIdx.x * 1024 + t;
#pragma unroll
    for (int r = 0; r < 4; ++r) {
        int a = idx + r * 256;
        if (a < NA) {
            u32 bb = sbits[a];
            if ((bb >> 21) == prefix) atomicAdd(&lh[(bb >> 10) & 0x7FFu], 1u);
        }
    }
    __syncthreads();
    for (int i = t; i < 2048; i += 256) { u32 h = lh[i]; if (h) atomicAdd(&hist1[i], h); }
    if (t == 0)
        is_last = (__hip_atomic_fetch_add(&state[6], 1u, __ATOMIC_ACQ_REL,
                                          __HIP_MEMORY_SCOPE_AGENT) == gridDim.x - 1);
    __syncthreads();
    if (is_last && t < 64) pick_body(state, hist1, 1);
}

// collect: EXACTLY 256 blocks (body covers NA via 4 strided 65536-segments).
__global__ __launch_bounds__(256) void k_collect(const u32* __restrict__ sbits,
                                                 u32* state, u64* __restrict__ cand) {
    __shared__ u64 lbuf[1024];
    __shared__ u32 lcount;
    __shared__ u32 gbase;
    int t = threadIdx.x;
    if (t == 0) lcount = 0;
    __syncthreads();
    u32 pivot = state[2];
#pragma unroll
    for (int r = 0; r < 4; ++r) {
        int a = blockIdx.x * 256 + t + r * 65536;
        if (a < NA) {
            u32 b = sbits[a];
            if (b != 0u && b >= pivot) {
                u32 s = atomicAdd(&lcount, 1u);
                if (s < 1024u) lbuf[s] = ((u64)b << 32) | (u32)(~(u32)a);
            }
        }
    }
    __syncthreads();
    u32 n = lcount; if (n > 1024u) n = 1024u;
    if (t == 0 && n > 0) gbase = atomicAdd(&state[3], n);
    __syncthreads();
    if (n > 0) {
        u32 base = gbase;
        for (u32 i = t; i < n; i += 256) {
            u32 slot = base + i;
            if (slot < CAP) cand[slot] = lbuf[i];
        }
    }
}

__global__ __launch_bounds__(256) void k_rank(const u32* __restrict__ state,
                                              const u64* __restrict__ cand,
                                              u32* __restrict__ canda, u32* __restrict__ cands,
                                              float4* __restrict__ boxesg,
                                              const float* __restrict__ anchors,
                                              const float* __restrict__ reg) {
    __shared__ u64 tile[CAP];
    __shared__ u32 pr2[16][17];
    int t = threadIdx.x;
    int n = (int)state[3]; if (n > CAP) n = CAP;
    for (int i = t; i < CAP; i += 256) tile[i] = (i < n) ? cand[i] : 0ull;
    if (blockIdx.x == 0) {
        for (int i = n + t; i < 2048; i += 256) {
            canda[i] = 0u; cands[i] = 0u;
            boxesg[i] = make_float4(0.f, 0.f, 0.f, 0.f);
        }
    }
    __syncthreads();
    int li = t & 15, seg = t >> 4;
    u64 my = tile[blockIdx.x * 16 + li];
    u32 r = 0;
    int j0 = seg * 256;
#pragma unroll 8
    for (int j = j0; j < j0 + 256; ++j) r += (tile[j] > my) ? 1u : 0u;
    pr2[li][seg] = r;
    __syncthreads();
    if (t < 16) {
        int ci = blockIdx.x * 16 + t;
        if (ci < n) {
            u32 rk = 0;
#pragma unroll
            for (int s = 0; s < 16; ++s) rk += pr2[t][s];
            u64 kx = tile[ci];
            u32 a = ~((u32)kx);
            if (rk < 2048u) {
                canda[rk] = a;
                cands[rk] = (u32)(kx >> 32);
                boxesg[rk] = decode_box(anchors, reg, a);
            }
        }
    }
}

// IoU bitmask, transposed supT.
__global__ __launch_bounds__(256) void k_iou(const float4* __restrict__ boxesg,
                                             u64* __restrict__ supT) {
    __shared__ float4 jb[4][64];
    int t = threadIdx.x;
    int w = t >> 6, lane = t & 63;
    int W = blockIdx.x * 4 + w;
    int bi = W >> 5, bj = W & 31;
    int j0 = bj * 64;
    jb[w][lane] = boxesg[j0 + lane];
    __syncthreads();
    int i = bi * 64 + lane;
    if (i >= KP) return;
    u64 word = 0ull;
    if (bj >= bi) {
        int jn = KP - j0; if (jn > 64) jn = 64;
        float4 bx = boxesg[i];
        float ai = (bx.z - bx.x) * (bx.w - bx.y);
        for (int jj = 0; jj < jn; ++jj) {
            if (j0 + jj <= i) continue;
            float4 b2 = jb[w][jj];
            float aj = (b2.z - b2.x) * (b2.w - b2.y);
            float xx1 = fmaxf(bx.x, b2.x), yy1 = fmaxf(bx.y, b2.y);
            float xx2 = fminf(bx.z, b2.z), yy2 = fminf(bx.w, b2.w);
            float iw = xx2 - xx1; if (iw < 0.f) iw = 0.f;
            float ih = yy2 - yy1; if (ih < 0.f) ih = 0.f;
            float inter = iw * ih;
            float iou = inter / (ai + aj - inter + 1e-9f);
            if (iou > 0.1f) word |= (1ull << jj);
        }
    }
    supT[(size_t)bj * 2048 + i] = word;
}

// serial greedy NMS, producer/consumer: 4 waves, 1 block.
//  wave 0: greedy decisions — LDS/registers ONLY on the critical path.
//  wave 1: folds kept rows into LDS `removed` (lag-2 slack absorbs gather latency).
//  waves 2,3: pre-stage all myw words (64KB) + cands into LDS.
__global__ __launch_bounds__(256, 1) void k_scan(const u64* __restrict__ supT,
                                                 const u32* __restrict__ cands,
                                                 const u32* __restrict__ canda,
                                                 const u32* __restrict__ amax,
                                                 const float4* __restrict__ boxesg,
                                                 float* __restrict__ out) {
    __shared__ u64 stage[16][4][128];    // 64 KB  [C][word][row]
    __shared__ float scnd[2048];
    __shared__ int klist[2048];
    __shared__ int kcAt[17];
    __shared__ u32 removedLo[32], removedHi[32];
    __shared__ u32 stage_done[16];
    __shared__ u32 kdone;
    __shared__ u32 fold_done;

    int t = threadIdx.x;
    int wv = t >> 6, lane = t & 63;
    if (t < 16) stage_done[t] = 0;
    if (t < 32) { removedLo[t] = 0; removedHi[t] = 0; }
    if (t == 0) { kdone = 0; fold_done = 0; kcAt[0] = 0; }
    __syncthreads();

    if (wv >= 2) {
        for (int C = wv - 2; C < 16; C += 2) {
            u64 v[8];
#pragma unroll
            for (int w = 0; w < 4; ++w) {
                int wa = 2 * C + w;
                v[2 * w]     = supT[(size_t)wa * 2048 + 128 * C + lane];
                v[2 * w + 1] = supT[(size_t)wa * 2048 + 128 * C + 64 + lane];
            }
            float c0 = __uint_as_float(cands[128 * C + lane]);
            float c1 = __uint_as_float(cands[128 * C + 64 + lane]);
#pragma unroll
            for (int w = 0; w < 4; ++w) {
                stage[C][w][lane] = v[2 * w];
                stage[C][w][64 + lane] = v[2 * w + 1];
            }
            scnd[128 * C + lane] = c0;
            scnd[128 * C + 64 + lane] = c1;
            __hip_atomic_store(&stage_done[C], 1u, __ATOMIC_RELEASE, WG);
        }
        return;
    }

    if (wv == 1) {
        for (int C = 0; C < 15; ++C) {
            while (__hip_atomic_load(&kdone, __ATOMIC_ACQUIRE, WG) <= (u32)C) {}
            int lo = kcAt[C], hi = kcAt[C + 1];
            int n = hi - lo;
            u64 acc = 0ull;
#pragma unroll
            for (int q = 0; q < 32; ++q) {
                int row = (q < n) ? klist[lo + q] : -1;
                u64 v = (row >= 0 && lane < 32)
                      ? supT[(size_t)lane * 2048 + row] : 0ull;
                acc |= v;
            }
            for (int q = 32; q < n; ++q) {
                int row = klist[lo + q];
                if (lane < 32) acc |= supT[(size_t)lane * 2048 + row];
            }
            if (lane < 32 && acc) {
                __hip_atomic_fetch_or(&removedLo[lane], (u32)acc, __ATOMIC_RELAXED, WG);
                __hip_atomic_fetch_or(&removedHi[lane], (u32)(acc >> 32), __ATOMIC_RELAXED, WG);
            }
            __hip_atomic_store(&fold_done, (u32)(C + 1), __ATOMIC_RELEASE, WG);
        }
        return;
    }

    // wave 0: greedy
    u64 carry0 = 0ull, carry1 = 0ull;
    int kc = 0;
    for (int C = 0; C < 16; ++C) {
        while (__hip_atomic_load(&stage_done[C], __ATOMIC_ACQUIRE, WG) == 0u) {}
        u64 m00 = stage[C][0][lane];
        u64 m01 = stage[C][1][lane];
        u64 m02 = stage[C][2][lane];
        u64 m03 = stage[C][3][lane];
        u64 m11 = stage[C][1][64 + lane];
        u64 m12 = stage[C][2][64 + lane];
        u64 m13 = stage[C][3][64 + lane];
        float cv0 = scnd[128 * C + lane];
        float cv1 = scnd[128 * C + 64 + lane];

        if (C >= 2) {
            while (__hip_atomic_load(&fold_done, __ATOMIC_ACQUIRE, WG) < (u32)(C - 1)) {}
        }
        u64 r0w = ((u64)removedHi[2 * C] << 32) | removedLo[2 * C];
        u64 r1w = ((u64)removedHi[2 * C + 1] << 32) | removedLo[2 * C + 1];
        u64 curw0 = carry0 | r0w;
        u64 curw1 = carry1 | r1w;
        u64 vm0 = __ballot(cv0 > SCORE_TH);
        u64 vm1 = __ballot(cv1 > SCORE_TH);
        if (C == 15) vm1 &= (1ull << (KP - 15 * 128 - 64)) - 1ull;

        u64 km0 = 0ull, km1 = 0ull, nc2 = 0ull, nc3 = 0ull;
        u64 rem0 = vm0 & ~curw0;
        while (rem0) {
            int bb = (int)__builtin_ctzll(rem0);
            km0 |= (1ull << bb);
            curw0 |= readlane_u64(m00, bb);
            curw1 |= readlane_u64(m01, bb);
            nc2   |= readlane_u64(m02, bb);
            nc3   |= readlane_u64(m03, bb);
            rem0 &= ~curw0;
            rem0 &= ~(1ull << bb);
        }
        u64 rem1 = vm1 & ~curw1;
        while (rem1) {
            int bb = (int)__builtin_ctzll(rem1);
            km1 |= (1ull << bb);
            curw1 |= readlane_u64(m11, bb);
            nc2   |= readlane_u64(m12, bb);
            nc3   |= readlane_u64(m13, bb);
            rem1 &= ~curw1;
            rem1 &= ~(1ull << bb);
        }

        int base = C * 128;
        int n0 = (int)__popcll(km0);
        if ((km0 >> lane) & 1ull)
            klist[kc + (int)__popcll(km0 & ((1ull << lane) - 1ull))] = base + lane;
        if ((km1 >> lane) & 1ull)
            klist[kc + n0 + (int)__popcll(km1 & ((1ull << lane) - 1ull))] = base + 64 + lane;
        kc += n0 + (int)__popcll(km1);
        if (lane == 0) kcAt[C + 1] = kc;
        carry0 = nc2; carry1 = nc3;
        __hip_atomic_store(&kdone, (u32)(C + 1), __ATOMIC_RELEASE, WG);

        if (kc >= MD) {
            if (lane == 0) {
                for (int C2 = C + 1; C2 < 16; ++C2) kcAt[C2 + 1] = kc;
            }
            __hip_atomic_store(&kdone, 16u, __ATOMIC_RELEASE, WG);
            break;
        }
    }

    // fused output: 300 slots
    int myci[5];
    u32 mya[5];
#pragma unroll
    for (int r = 0; r < 5; ++r) {
        int s = lane + r * 64;
        myci[r] = (s < MD && s < kc) ? klist[s] : -1;
    }
#pragma unroll
    for (int r = 0; r < 5; ++r) mya[r] = (myci[r] >= 0) ? canda[myci[r]] : 0u;
#pragma unroll
    for (int r = 0; r < 5; ++r) {
        int s = lane + r * 64;
        if (s >= MD) continue;
        if (myci[r] >= 0) {
            int ci = myci[r];
            u32 a = mya[r];
            u32 aa = (a >= NA) ? 0u : a;
            float4 bx = boxesg[ci];
            out[s] = __uint_as_float(cands[ci]);
            out[MD + s] = (float)amax[aa];
            out[2 * MD + 4 * s + 0] = bx.x;
            out[2 * MD + 4 * s + 1] = bx.y;
            out[2 * MD + 4 * s + 2] = bx.z;
            out[2 * MD + 4 * s + 3] = bx.w;
            out[6 * MD + s] = (float)a;
            out[7 * MD + s] = 1.0f;
        } else {
            out[s] = 0.f;
            out[MD + s] = 0.f;
            out[2 * MD + 4 * s + 0] = 0.f;
            out[2 * MD + 4 * s + 1] = 0.f;
            out[2 * MD + 4 * s + 2] = 0.f;
            out[2 * MD + 4 * s + 3] = 0.f;
            out[6 * MD + s] = -1.0f;
            out[7 * MD + s] = 0.f;
        }
    }
}

extern "C" void kernel_launch(void* const* d_in, const int* in_sizes, int n_in,
                              void* d_out, int out_size, void* d_ws, size_t ws_size,
                              hipStream_t stream) {
    const float* anchors = (const float*)d_in[1];
    const float* reg     = (const float*)d_in[2];
    const float* cls     = (const float*)d_in[3];
    float* out = (float*)d_out;
    char* ws = (char*)d_ws;

    u32* sbits    = (u32*)(ws + 0);
    u32* amax     = (u32*)(ws + 1000000);
    u32* state    = (u32*)(ws + 2000000);
    u32* hist0    = (u32*)(ws + 2000064);
    u32* hist1    = (u32*)(ws + 2008256);
    u64* cand     = (u64*)(ws + 2016448);
    u32* canda    = (u32*)(ws + 2049216);
    u32* cands    = (u32*)(ws + 2057408);
    float4* boxesg= (float4*)(ws + 2065600);
    u64* supT     = (u64*)(ws + 2098368);

    hipLaunchKernelGGL(k_score, dim3((NA + 255) / 256), dim3(256), 0, stream,
                       cls, sbits, amax, state, hist0, hist1);
    hipLaunchKernelGGL(k_hist0, dim3((NA + 1023) / 1024), dim3(256), 0, stream,
                       sbits, hist0, state);
    hipLaunchKernelGGL(k_hist1, dim3((NA + 1023) / 1024), dim3(256), 0, stream,
                       sbits, hist1, state);
    hipLaunchKernelGGL(k_collect, dim3(256), dim3(256), 0, stream,
                       sbits, state, cand);
    hipLaunchKernelGGL(k_rank, dim3(256), dim3(256), 0, stream,
                       state, cand, canda, cands, boxesg, anchors, reg);
    hipLaunchKernelGGL(k_iou, dim3(256), dim3(256), 0, stream, boxesg, supT);
    hipLaunchKernelGGL(k_scan, dim3(1), dim3(256), 0, stream,
                       supT, cands, canda, amax, boxesg, out);
}